// Round 16
// baseline (37.094 us; speedup 1.0000x reference)
//
#include <hip/hip_runtime.h>
#include <math.h>

// B=1, N=4096 queries, F=4096 faces (fixed by reference setup_inputs).
#define N_Q 4096
#define N_F 4096
#define QPT 1                  // one query per thread
#define FSPLIT 64              // 16 q-blocks x 64 f-splits = 1024 blocks (16 waves/CU)
#define FT (N_F / FSPLIT)      // 64 faces per block
#define INV_2PI 0.15915494309189535f

// Fast atan2: 6-coeff odd minimax poly on [0,1] (max err ~1e-5 rad).
__device__ __forceinline__ float fast_atan2f(float y, float x) {
    const float pi   = 3.14159265358979f;
    const float pi_2 = 1.57079632679490f;
    float ax = fabsf(x), ay = fabsf(y);
    float mx = fmaxf(ax, ay), mn = fminf(ax, ay);
    mx = fmaxf(mx, 1e-30f);                        // 0/0 -> 0, no NaN
    float t = mn * __builtin_amdgcn_rcpf(mx);      // t in [0,1]
    float s = t * t;
    float p =              -0.0117212f;
    p = fmaf(p, s,  0.05265332f);
    p = fmaf(p, s, -0.11643287f);
    p = fmaf(p, s,  0.19354346f);
    p = fmaf(p, s, -0.33262347f);
    p = fmaf(p, s,  0.99997726f);
    float r = p * t;                               // atan(t) on [0, pi/4]
    r = (ay > ax) ? (pi_2 - r) : r;
    r = (x < 0.0f) ? (pi - r) : r;
    return copysignf(r, y);
}

// Angle-merge (proven R13/R14): atan2 sum -> one atan2 + exact 2*pi wraps.
__device__ __forceinline__ void merge_angle(
    float y1, float x1, float y2, float x2,
    float& ym, float& xm, float& w)
{
    ym = fmaf(y1, x2, y2 * x1);
    xm = fmaf(-y1, y2, x1 * x2);
    const float c = copysignf(1.0f, y1) + copysignf(1.0f, y2);  // +-2 or 0
    w += (ym * c < 0.0f) ? 0.5f * c : 0.0f;                     // +-1 wrap
}

// (det, den) from precomputed face constants (25 VALU + 3 trans).
__device__ __forceinline__ void build_dn(
    float qx, float qy, float qz, float th,
    float4 A, float4 B, float4 C, float4 Nv, float4 K,
    float& det, float& den)
{
    const float da = fmaf(-qx, A.x, fmaf(-qy, A.y, fmaf(-qz, A.z, th)));
    const float db = fmaf(-qx, B.x, fmaf(-qy, B.y, fmaf(-qz, B.z, th)));
    const float dc = fmaf(-qx, C.x, fmaf(-qy, C.y, fmaf(-qz, C.z, th)));
    det = fmaf(-qx, Nv.x, fmaf(-qy, Nv.y, fmaf(-qz, Nv.z, Nv.w)));

    const float na = __builtin_amdgcn_sqrtf(fmaf(2.0f, da, A.w));
    const float nb = __builtin_amdgcn_sqrtf(fmaf(2.0f, db, B.w));
    const float nc = __builtin_amdgcn_sqrtf(fmaf(2.0f, dc, C.w));

    const float ab = K.x + (da + db);
    const float bc = K.y + (db + dc);
    const float ac = K.z + (da + dc);

    den = fmaf(na * nb, nc, fmaf(bc, na, fmaf(ac, nb, ab * nc)));
}

// One-time per-face constants -> d_ws (R7's kernel, verified).
__global__ __launch_bounds__(256) void face_const_kernel(
    const float* __restrict__ fc, float4* __restrict__ cst)
{
    const int f = blockIdx.x * 256 + threadIdx.x;
    if (f >= N_F) return;
    const float* v = fc + (size_t)f * 9;
    const float ax = v[0], ay = v[1], az = v[2];
    const float bx = v[3], by = v[4], bz = v[5];
    const float cx = v[6], cy = v[7], cz = v[8];
    const float ux = by*cz - bz*cy, uy = bz*cx - bx*cz, uz = bx*cy - by*cx; // bxc
    const float vx = cy*az - cz*ay, vy = cz*ax - cx*az, vz = cx*ay - cy*ax; // cxa
    const float wx = ay*bz - az*by, wy = az*bx - ax*bz, wz = ax*by - ay*bx; // axb
    const float D  = ax*ux + ay*uy + az*uz;
    float4* o = cst + (size_t)f * 5;
    o[0] = make_float4(ax, ay, az, ax*ax + ay*ay + az*az);
    o[1] = make_float4(bx, by, bz, bx*bx + by*by + bz*bz);
    o[2] = make_float4(cx, cy, cz, cx*cx + cy*cy + cz*cz);
    o[3] = make_float4(ux + vx + wx, uy + vy + wy, uz + vz + wz, D);
    o[4] = make_float4(ax*bx + ay*by + az*bz,
                       bx*cx + by*cy + bz*cz,
                       ax*cx + ay*cy + az*cz, 0.0f);
}

// Main: zero LDS, zero staging. Face constants read at WAVE-UNIFORM
// addresses (blockIdx.y + uniform loop idx) -> scalar s_load broadcast on
// the SMEM pipe; inner loop is pure VALU math: 4 builds -> 3 merges -> 1
// atan2 per 4 faces with exact wrap tracking.
__global__ __launch_bounds__(256) void winding_kernel(
    const float* __restrict__ qp,   // [N_Q][3]
    const float4* __restrict__ cst, // [N_F][5]
    float* __restrict__ out)        // [N_Q]
{
    const int q  = blockIdx.x * 256 + threadIdx.x;   // one query per thread
    const int f0 = blockIdx.y * FT;

    const float qx = qp[q*3+0], qy = qp[q*3+1], qz = qp[q*3+2];
    const float th = 0.5f * fmaf(qx, qx, fmaf(qy, qy, qz * qz));

    float s = 0.0f, w = 0.0f;

    #pragma unroll 2
    for (int f = 0; f < FT; f += 4) {
        const float4* c0 = cst + (size_t)(f0 + f) * 5;
        const float4 A0 = c0[0],  B0 = c0[1],  C0 = c0[2],  N0 = c0[3],  K0 = c0[4];
        const float4 A1 = c0[5],  B1 = c0[6],  C1 = c0[7],  N1 = c0[8],  K1 = c0[9];
        const float4 A2 = c0[10], B2 = c0[11], C2 = c0[12], N2 = c0[13], K2 = c0[14];
        const float4 A3 = c0[15], B3 = c0[16], C3 = c0[17], N3 = c0[18], K3 = c0[19];

        float d0,n0,d1,n1,d2,n2,d3,n3;
        build_dn(qx,qy,qz,th, A0,B0,C0,N0,K0, d0,n0);
        build_dn(qx,qy,qz,th, A1,B1,C1,N1,K1, d1,n1);
        build_dn(qx,qy,qz,th, A2,B2,C2,N2,K2, d2,n2);
        build_dn(qx,qy,qz,th, A3,B3,C3,N3,K3, d3,n3);

        float ya,xa,yb,xb,Y,X;
        merge_angle(d0,n0, d1,n1, ya,xa, w);
        merge_angle(d2,n2, d3,n3, yb,xb, w);
        merge_angle(ya,xa, yb,xb, Y,X, w);
        s += fast_atan2f(Y, X);
    }

    atomicAdd(&out[q], fmaf(s, INV_2PI, w));   // winding = s/(2pi) + wraps
}

extern "C" void kernel_launch(void* const* d_in, const int* in_sizes, int n_in,
                              void* d_out, int out_size, void* d_ws, size_t ws_size,
                              hipStream_t stream) {
    const float* qp = (const float*)d_in[0];   // query_points (1,4096,3) f32
    const float* fc = (const float*)d_in[1];   // face_coord   (1,4096,3,3) f32
    float* out = (float*)d_out;                // (1,4096) f32
    float4* cst = (float4*)d_ws;               // 4096*5*16B = 328 KB workspace

    // Harness poisons d_out once and never re-poisons between replays:
    // we accumulate with atomics, so zero it ourselves every call.
    hipMemsetAsync(out, 0, (size_t)out_size * sizeof(float), stream);
    face_const_kernel<<<dim3(N_F / 256), dim3(256), 0, stream>>>(fc, cst);

    dim3 grid(N_Q / 256, FSPLIT);
    winding_kernel<<<grid, dim3(256), 0, stream>>>(qp, cst, out);
}